// Round 1
// baseline (259.377 us; speedup 1.0000x reference)
//
#include <hip/hip_runtime.h>
#include <math.h>

#define TOKENS 16384
#define DMODEL 2048
#define NEXP   64
#define TOPK   8
#define BM     32            // tokens per block
#define BK     64            // k per chunk
#define NCHUNK (DMODEL / BK) // 32
#define ROWU   72            // padded LDS row (64 data + 8 pad shorts) = 144 B
#define WTILEU (NEXP * ROWU) // 4608 shorts per W split-tile
#define WT3PAD 14336         // 3 tiles (13824) rounded to 7x4096 B copy rounds

typedef unsigned short u16;
typedef float f32x4 __attribute__((ext_vector_type(4)));
typedef short s16x8 __attribute__((ext_vector_type(8)));

// RNE fp32 -> bf16, also returning the rounded-back fp32 value.
__device__ __forceinline__ u16 f2bf(float f, float& back) {
    unsigned u = __float_as_uint(f);
    unsigned r = u + 0x7fffu + ((u >> 16) & 1u);
    back = __uint_as_float(r & 0xffff0000u);
    return (u16)(r >> 16);
}

__device__ __forceinline__ void gload_lds16(const void* g, void* l) {
    __builtin_amdgcn_global_load_lds(
        (const __attribute__((address_space(1))) unsigned int*)g,
        (__attribute__((address_space(3))) unsigned int*)l, 16, 0, 0);
}

// Kernel 1: pre-split W (fp32) into 3 bf16 terms, stored as the exact LDS
// tile image (row pad 72, chunk-major, 28672 B per chunk) so the main kernel
// can stream it with linear global_load_lds copies.
// Exactness: a1+a2+a3 carries >=24 mantissa bits; subtractions are exact
// (Sterbenz), so W is represented to ~2^-27 relative.
__global__ __launch_bounds__(256) void wconv(
    const float* __restrict__ W, u16* __restrict__ wimg)
{
    const int id = blockIdx.x * 256 + threadIdx.x;  // 64*2048 threads
    const int e = id >> 11;
    const int k = id & 2047;
    const float x = W[id];
    float f1, f2, fd;
    const u16 a = f2bf(x, f1);
    const float d1 = x - f1;       // exact
    const u16 b = f2bf(d1, f2);
    const float d2 = d1 - f2;      // exact
    const u16 c = f2bf(d2, fd);
    u16* base = wimg + (size_t)(k >> 6) * WT3PAD + e * ROWU + (k & 63);
    base[0]          = a;
    base[WTILEU]     = b;
    base[2 * WTILEU] = c;
}

// Kernel 2: fused router. Per block: 32 tokens x 64 experts over K=2048.
//  - math on the MFMA pipe (was idle: MfmaUtil=0) via exact 3-term bf16
//    split, 6 cross-product passes -> fp32-grade products, fp64 flush per
//    64-k chunk -> numerics equivalent to the previous fp64 kernel.
//  - x reg-staged + split in-kernel; W streamed pre-split via global_load_lds
//    (double-buffered, issued during compute so L2 latency hides).
//  - LDS rows padded to 144 B: b128 fragment reads are minimal-8-cycle
//    (row-major stride-128 would be a 16-way conflict, G4).
//  - A/B fragments use the SAME k-ordering convention, so the hardware's
//    internal k permutation cancels; C/D mapping per m89.
//  - top-8 fused in-block (verified shuffle epilogue), no part workspace:
//    kills 32 MB write + 32 MB read + second big kernel.
__global__ __launch_bounds__(256) void router_fused(
    const float* __restrict__ x, const u16* __restrict__ wimg,
    const float* __restrict__ bias, float* __restrict__ out_w,
    float* __restrict__ out_i)
{
    __shared__ __align__(16) u16 xs[3][BM * ROWU];   // 13824 B
    __shared__ __align__(16) u16 wsb[2][WT3PAD];     // 57344 B (double buffer)
    __shared__ float lg[BM][NEXP + 4];               // 8704 B  (total 79872 B)

    const int tid  = threadIdx.x;
    const int lane = tid & 63;
    const int w    = tid >> 6;   // wave 0..3
    const int wr   = w >> 1;     // token half (16 rows)
    const int wc   = w & 1;      // expert half (32 cols)
    const size_t tokBase = (size_t)blockIdx.x * BM;

    // x staging: thread = (row 0..31, oct 0..7), 8 consecutive floats
    const int srow = tid >> 3;
    const int soct = tid & 7;
    const float* xp = x + (tokBase + srow) * DMODEL + soct * 8;

    // fragment addressing (shorts): free index = lane&15, k-part = lane>>4
    const int arow  = wr * 16 + (lane & 15);
    const int kq    = (lane >> 4) * 8;
    const int brow0 = wc * 32 + (lane & 15);

    f32x4  acc[2][2];   // [ks][nt] fp32 MFMA accumulators
    double accd[2][4];  // [nt][reg] fp64 running sums
#pragma unroll
    for (int i = 0; i < 2; ++i)
#pragma unroll
        for (int j = 0; j < 2; ++j)
            acc[i][j] = (f32x4){0.f, 0.f, 0.f, 0.f};
#pragma unroll
    for (int j = 0; j < 2; ++j)
#pragma unroll
        for (int r = 0; r < 4; ++r) accd[j][r] = 0.0;

    // W chunk copy: 28672 B as 7 rounds x (4 waves x 64 lanes x 16 B)
    const char* wgbase = (const char*)wimg;
#define WCOPY(tt, buf)                                                        \
    {                                                                         \
        const char* gsrc_ = wgbase + (size_t)(tt) * (WT3PAD * 2) + w * 1024 + \
                            lane * 16;                                        \
        char* ldst_ = (char*)&wsb[buf][0] + w * 1024;                         \
        _Pragma("unroll") for (int r_ = 0; r_ < 7; ++r_)                      \
            gload_lds16(gsrc_ + r_ * 4096, ldst_ + r_ * 4096);                \
    }

    // prologue: chunk 0 in flight
    float4 xa = *(const float4*)(xp);
    float4 xb = *(const float4*)(xp + 4);
    WCOPY(0, 0);

    for (int t = 0; t < NCHUNK; ++t) {
        __syncthreads();  // prev readers done; drains W copy for chunk t
        {   // split x regs -> 3 bf16 LDS tiles
            float xv[8] = {xa.x, xa.y, xa.z, xa.w, xb.x, xb.y, xb.z, xb.w};
            s16x8 va, vb, vc;
#pragma unroll
            for (int j = 0; j < 8; ++j) {
                float f1, f2, fd;
                const u16 a1 = f2bf(xv[j], f1);
                const float d1 = xv[j] - f1;  // exact
                const u16 a2 = f2bf(d1, f2);
                const float d2 = d1 - f2;     // exact
                const u16 a3 = f2bf(d2, fd);
                va[j] = (short)a1; vb[j] = (short)a2; vc[j] = (short)a3;
            }
            const int ub = srow * ROWU + soct * 8;  // 16B-aligned
            *(s16x8*)&xs[0][ub] = va;
            *(s16x8*)&xs[1][ub] = vb;
            *(s16x8*)&xs[2][ub] = vc;
        }
        __syncthreads();
        if (t + 1 < NCHUNK) {  // next chunk's loads ride under this compute
            xp += BK;
            xa = *(const float4*)(xp);
            xb = *(const float4*)(xp + 4);
            WCOPY(t + 1, (t + 1) & 1);
        }

        const u16* wb = &wsb[t & 1][0];
#pragma unroll
        for (int ks = 0; ks < 2; ++ks) {
            const int ko = ks * 32 + kq;
            const s16x8 a1 = *(const s16x8*)&xs[0][arow * ROWU + ko];
            const s16x8 a2 = *(const s16x8*)&xs[1][arow * ROWU + ko];
            const s16x8 a3 = *(const s16x8*)&xs[2][arow * ROWU + ko];
#pragma unroll
            for (int nt = 0; nt < 2; ++nt) {
                const int br = (brow0 + nt * 16) * ROWU + ko;
                const s16x8 b1 = *(const s16x8*)&wb[0 * WTILEU + br];
                const s16x8 b2 = *(const s16x8*)&wb[1 * WTILEU + br];
                const s16x8 b3 = *(const s16x8*)&wb[2 * WTILEU + br];
                f32x4 t0 = acc[ks][nt];
                t0 = __builtin_amdgcn_mfma_f32_16x16x32_bf16(a1, b1, t0, 0, 0, 0);
                t0 = __builtin_amdgcn_mfma_f32_16x16x32_bf16(a1, b2, t0, 0, 0, 0);
                t0 = __builtin_amdgcn_mfma_f32_16x16x32_bf16(a2, b1, t0, 0, 0, 0);
                t0 = __builtin_amdgcn_mfma_f32_16x16x32_bf16(a1, b3, t0, 0, 0, 0);
                t0 = __builtin_amdgcn_mfma_f32_16x16x32_bf16(a3, b1, t0, 0, 0, 0);
                t0 = __builtin_amdgcn_mfma_f32_16x16x32_bf16(a2, b2, t0, 0, 0, 0);
                acc[ks][nt] = t0;
            }
        }
        // fp64 flush once per 64-k chunk (numerics == previous fp64 kernel)
#pragma unroll
        for (int nt = 0; nt < 2; ++nt)
#pragma unroll
            for (int r = 0; r < 4; ++r) {
                accd[nt][r] += (double)acc[0][nt][r] + (double)acc[1][nt][r];
                acc[0][nt][r] = 0.f;
                acc[1][nt][r] = 0.f;
            }
    }

    // C/D mapping (m89): col = lane&15, row = (lane>>4)*4 + reg
#pragma unroll
    for (int nt = 0; nt < 2; ++nt)
#pragma unroll
        for (int r = 0; r < 4; ++r) {
            const int row = wr * 16 + (lane >> 4) * 4 + r;
            const int col = wc * 32 + nt * 16 + (lane & 15);
            lg[row][col] = (float)accd[nt][r];
        }
    __syncthreads();

    // fused top-8: wave handles 8 tokens, lane = expert (verified epilogue)
    const float be = bias[lane];
#pragma unroll
    for (int i = 0; i < 8; ++i) {
        const int tl = w * 8 + i;
        float v = lg[tl][lane] + be;
        const int myi = lane;
        float bv = 0.0f; int bi = 0;
#pragma unroll
        for (int r = 0; r < TOPK; ++r) {
            float mv = v; int mi = myi;
#pragma unroll
            for (int off = 32; off > 0; off >>= 1) {
                const float ov = __shfl_xor(mv, off, 64);
                const int   oi = __shfl_xor(mi, off, 64);
                if (ov > mv || (ov == mv && oi < mi)) { mv = ov; mi = oi; }
            }
            if (lane == r) { bv = mv; bi = mi; }
            if (myi == mi) { v = -INFINITY; }
        }
        if (lane < TOPK) {
            const size_t tok = tokBase + tl;
            out_w[tok * TOPK + lane] = 1.0f / (1.0f + expf(-bv));
            out_i[tok * TOPK + lane] = (float)bi;
        }
    }
}

extern "C" void kernel_launch(void* const* d_in, const int* in_sizes, int n_in,
                              void* d_out, int out_size, void* d_ws, size_t ws_size,
                              hipStream_t stream) {
    const float* x    = (const float*)d_in[0];   // [4,4096,2048]
    const float* W    = (const float*)d_in[1];   // [64,2048]
    const float* bias = (const float*)d_in[2];   // [64]
    float* out_w = (float*)d_out;                          // [16384,8]
    float* out_i = (float*)d_out + (size_t)TOKENS * TOPK;  // [16384,8] as float
    u16* wimg = (u16*)d_ws;  // 32 * 28672 B = 917504 B of W split-image

    wconv<<<dim3((NEXP * DMODEL) / 256), 256, 0, stream>>>(W, wimg);
    router_fused<<<dim3(TOKENS / BM), 256, 0, stream>>>(x, wimg, bias, out_w, out_i);
}

// Round 2
// 249.596 us; speedup vs baseline: 1.0392x; 1.0392x over previous
//
#include <hip/hip_runtime.h>
#include <math.h>

#define TOKENS 16384
#define DMODEL 2048
#define NEXP   64
#define TOPK   8
#define BM     32            // tokens per block
#define BK     64            // k per chunk
#define NCHUNK (DMODEL / BK) // 32
#define WCHUNKB 24576        // bytes of W image per chunk (24 frags x 1024 B)
#define WSHORTS 12288        // shorts per chunk image

typedef unsigned short u16;
typedef float f32x4 __attribute__((ext_vector_type(4)));
typedef short s16x8 __attribute__((ext_vector_type(8)));

// RNE fp32 -> bf16, also returning the rounded-back fp32 value.
// (bit-identical to the passing R1 kernel's split -> identical logits)
__device__ __forceinline__ u16 f2bf(float f, float& back) {
    unsigned u = __float_as_uint(f);
    unsigned r = u + 0x7fffu + ((u >> 16) & 1u);
    back = __uint_as_float(r & 0xffff0000u);
    return (u16)(r >> 16);
}

// Kernel 1: pre-split W into 3 bf16 terms, stored in MFMA B-FRAGMENT ORDER:
// chunk c -> 24 fragments of 1024B, frag(tau,ks,eq) at ((tau*2+ks)*4+eq),
// lane l's 16B = expert eq*16+(l&15), k = c*64+ks*32+(l>>4)*8 .. +8.
// Main kernel then stages W with LINEAR lane*16 copies and reads B-frags at
// lane*16 -> zero LDS bank conflicts, zero padding.
__global__ __launch_bounds__(256) void wconv(
    const float* __restrict__ W, u16* __restrict__ wimg)
{
    const int id  = blockIdx.x * 256 + threadIdx.x;  // 16384 threads
    const int e   = id >> 8;     // expert 0..63
    const int ko8 = id & 255;    // k-oct 0..255
    const int k0  = ko8 * 8;
    const int c   = ko8 >> 3;          // chunk
    const int ks  = (ko8 >> 2) & 1;    // k-half within chunk
    const int hi  = ko8 & 3;           // lane>>4 part
    const int lane = hi * 16 + (e & 15);
    const int eq   = e >> 4;

    const float* src = W + (size_t)e * DMODEL + k0;
    const float4 f0 = *(const float4*)(src);
    const float4 f1 = *(const float4*)(src + 4);
    const float xe[8] = {f0.x, f0.y, f0.z, f0.w, f1.x, f1.y, f1.z, f1.w};
    s16x8 va, vb, vc;
#pragma unroll
    for (int j = 0; j < 8; ++j) {
        float b1, b2, b3;
        const u16 a1 = f2bf(xe[j], b1);
        const float d1 = xe[j] - b1;   // exact (Sterbenz)
        const u16 a2 = f2bf(d1, b2);
        const float d2 = d1 - b2;      // exact
        const u16 a3 = f2bf(d2, b3);
        va[j] = (short)a1; vb[j] = (short)a2; vc[j] = (short)a3;
    }
    u16* base = wimg + (size_t)c * WSHORTS + lane * 8;
    *(s16x8*)(base + ((0 * 2 + ks) * 4 + eq) * 512) = va;
    *(s16x8*)(base + ((1 * 2 + ks) * 4 + eq) * 512) = vb;
    *(s16x8*)(base + ((2 * 2 + ks) * 4 + eq) * 512) = vc;
}

// Kernel 2: fused router, latency-decoupled rewrite of R1 (same numerics).
//  - x: per-lane direct global->reg (coalesced 128B/token), split in-reg ->
//    A-fragments. No xs LDS, no staging barrier.
//  - W: reg-staged (plain dwordx4, NOT global_load_lds -> no vmcnt(0) drain
//    at barriers), issued 1 chunk ahead, ds_write late (T14), double-buffered
//    linear fragment-order LDS -> conflict-free lane*16 b128 reads.
//  - ONE __syncthreads per chunk (gates only LDS reuse, cheap lgkm).
//  - LDS 48KB (+8.5KB lg aliased on dead ws) -> 3 blocks/CU, 12 waves (was 8).
//  - MFMA pass order + per-64k fp64 flush identical to the PASSING R1 kernel
//    -> bit-identical logits -> identical outputs.
__global__ __launch_bounds__(256) void router_fused(
    const float* __restrict__ x, const u16* __restrict__ wimg,
    const float* __restrict__ bias, float* __restrict__ out_w,
    float* __restrict__ out_i)
{
    __shared__ __align__(16) u16 ws[2][WSHORTS];   // 49152 B total

    const int tid  = threadIdx.x;
    const int lane = tid & 63;
    const int w    = tid >> 6;   // wave 0..3
    const int wr   = w >> 1;     // token half (16 rows)
    const int wc   = w & 1;      // expert half (32 cols)
    const size_t tokBase = (size_t)blockIdx.x * BM;

    // A-side addressing: lane owns token wr*16+(lane&15), k-oct lane>>4
    const int arow = wr * 16 + (lane & 15);
    const float* xrow = x + (tokBase + arow) * (size_t)DMODEL + (lane >> 4) * 8;

    // B-side: fragment (tau,ks,eq) at ((tau*2+ks)*4+eq)*512 + lane*8 shorts
    const int eq0 = wc * 2;  // nt=0 -> eq0, nt=1 -> eq0+1

    f32x4  acc[2][2];   // [ks][nt]
    double accd[2][4];  // [nt][reg]
#pragma unroll
    for (int i = 0; i < 2; ++i)
#pragma unroll
        for (int j = 0; j < 2; ++j) acc[i][j] = (f32x4){0.f, 0.f, 0.f, 0.f};
#pragma unroll
    for (int j = 0; j < 2; ++j)
#pragma unroll
        for (int r = 0; r < 4; ++r) accd[j][r] = 0.0;

    // ---- prologue: stage chunk 0 ----
    const char* wg = (const char*)wimg + tid * 16;
    float4 wst[6];
#pragma unroll
    for (int r = 0; r < 6; ++r) wst[r] = *(const float4*)(wg + r * 4096);
    float4 xv[4];
#pragma unroll
    for (int ks = 0; ks < 2; ++ks) {
        xv[ks * 2 + 0] = *(const float4*)(xrow + ks * 32);
        xv[ks * 2 + 1] = *(const float4*)(xrow + ks * 32 + 4);
    }
    {
        char* wl = (char*)&ws[0][0] + tid * 16;
#pragma unroll
        for (int r = 0; r < 6; ++r) *(float4*)(wl + r * 4096) = wst[r];
    }
    __syncthreads();

    for (int t = 0; t < NCHUNK; ++t) {
        // 1) split current x regs -> A-fragments (frees xv)
        s16x8 af[3][2];
#pragma unroll
        for (int ks = 0; ks < 2; ++ks) {
            const float xe[8] = {xv[ks * 2].x,     xv[ks * 2].y,
                                 xv[ks * 2].z,     xv[ks * 2].w,
                                 xv[ks * 2 + 1].x, xv[ks * 2 + 1].y,
                                 xv[ks * 2 + 1].z, xv[ks * 2 + 1].w};
#pragma unroll
            for (int j = 0; j < 8; ++j) {
                float b1, b2, b3;
                const u16 a1 = f2bf(xe[j], b1);
                const float d1 = xe[j] - b1;
                const u16 a2 = f2bf(d1, b2);
                const float d2 = d1 - b2;
                const u16 a3 = f2bf(d2, b3);
                af[0][ks][j] = (short)a1;
                af[1][ks][j] = (short)a2;
                af[2][ks][j] = (short)a3;
            }
        }
        // 2) issue next chunk's loads (consumed at the END of this iter /
        //    TOP of next -> full-chunk latency window, no barrier drain)
        if (t + 1 < NCHUNK) {
            const float* xp = xrow + (size_t)(t + 1) * BK;
#pragma unroll
            for (int ks = 0; ks < 2; ++ks) {
                xv[ks * 2 + 0] = *(const float4*)(xp + ks * 32);
                xv[ks * 2 + 1] = *(const float4*)(xp + ks * 32 + 4);
            }
            const char* wgp = wg + (size_t)(t + 1) * WCHUNKB;
#pragma unroll
            for (int r = 0; r < 6; ++r) wst[r] = *(const float4*)(wgp + r * 4096);
        }
        // 3) compute chunk t from ws[t&1]
        const u16* wb = &ws[t & 1][0];
#pragma unroll
        for (int ks = 0; ks < 2; ++ks) {
#pragma unroll
            for (int nt = 0; nt < 2; ++nt) {
                const u16* bp = wb + (size_t)(eq0 + nt) * 512 + lane * 8;
                const s16x8 b1 = *(const s16x8*)(bp + ((0 * 2 + ks) * 4) * 512);
                const s16x8 b2 = *(const s16x8*)(bp + ((1 * 2 + ks) * 4) * 512);
                const s16x8 b3 = *(const s16x8*)(bp + ((2 * 2 + ks) * 4) * 512);
                f32x4 t0 = acc[ks][nt];
                t0 = __builtin_amdgcn_mfma_f32_16x16x32_bf16(af[0][ks], b1, t0, 0, 0, 0);
                t0 = __builtin_amdgcn_mfma_f32_16x16x32_bf16(af[0][ks], b2, t0, 0, 0, 0);
                t0 = __builtin_amdgcn_mfma_f32_16x16x32_bf16(af[1][ks], b1, t0, 0, 0, 0);
                t0 = __builtin_amdgcn_mfma_f32_16x16x32_bf16(af[0][ks], b3, t0, 0, 0, 0);
                t0 = __builtin_amdgcn_mfma_f32_16x16x32_bf16(af[2][ks], b1, t0, 0, 0, 0);
                t0 = __builtin_amdgcn_mfma_f32_16x16x32_bf16(af[1][ks], b2, t0, 0, 0, 0);
                acc[ks][nt] = t0;
            }
        }
        // 4) fp64 flush once per 64-k chunk (identical to R1)
#pragma unroll
        for (int nt = 0; nt < 2; ++nt)
#pragma unroll
            for (int r = 0; r < 4; ++r) {
                accd[nt][r] += (double)acc[0][nt][r] + (double)acc[1][nt][r];
                acc[0][nt][r] = 0.f;
                acc[1][nt][r] = 0.f;
            }
        // 5) write next W chunk to the other buffer (waits its vmcnt here)
        if (t + 1 < NCHUNK) {
            char* wl = (char*)&ws[(t + 1) & 1][0] + tid * 16;
#pragma unroll
            for (int r = 0; r < 6; ++r) *(float4*)(wl + r * 4096) = wst[r];
        }
        __syncthreads();
    }

    // ---- epilogue: logits exchange via lg aliased on dead ws ----
    float* lg = (float*)&ws[0][0];   // [32][68] fp32, 8704 B
#pragma unroll
    for (int nt = 0; nt < 2; ++nt)
#pragma unroll
        for (int r = 0; r < 4; ++r) {
            const int row = wr * 16 + (lane >> 4) * 4 + r;
            const int col = wc * 32 + nt * 16 + (lane & 15);
            lg[row * 68 + col] = (float)accd[nt][r];
        }
    __syncthreads();

    // fused top-8: wave handles 8 tokens, lane = expert (verified epilogue)
    const float be = bias[lane];
#pragma unroll
    for (int i = 0; i < 8; ++i) {
        const int tl = w * 8 + i;
        float v = lg[tl * 68 + lane] + be;
        const int myi = lane;
        float bv = 0.0f; int bi = 0;
#pragma unroll
        for (int r = 0; r < TOPK; ++r) {
            float mv = v; int mi = myi;
#pragma unroll
            for (int off = 32; off > 0; off >>= 1) {
                const float ov = __shfl_xor(mv, off, 64);
                const int   oi = __shfl_xor(mi, off, 64);
                if (ov > mv || (ov == mv && oi < mi)) { mv = ov; mi = oi; }
            }
            if (lane == r) { bv = mv; bi = mi; }
            if (myi == mi) { v = -INFINITY; }
        }
        if (lane < TOPK) {
            const size_t tok = tokBase + tl;
            out_w[tok * TOPK + lane] = 1.0f / (1.0f + expf(-bv));
            out_i[tok * TOPK + lane] = (float)bi;
        }
    }
}

extern "C" void kernel_launch(void* const* d_in, const int* in_sizes, int n_in,
                              void* d_out, int out_size, void* d_ws, size_t ws_size,
                              hipStream_t stream) {
    const float* x    = (const float*)d_in[0];   // [4,4096,2048]
    const float* W    = (const float*)d_in[1];   // [64,2048]
    const float* bias = (const float*)d_in[2];   // [64]
    float* out_w = (float*)d_out;                          // [16384,8]
    float* out_i = (float*)d_out + (size_t)TOKENS * TOPK;  // [16384,8] as float
    u16* wimg = (u16*)d_ws;  // 32 * 24576 B = 786432 B, fragment-ordered

    wconv<<<dim3((NEXP * DMODEL / 8) / 256), 256, 0, stream>>>(W, wimg);
    router_fused<<<dim3(TOKENS / BM), 256, 0, stream>>>(x, wimg, bias, out_w, out_i);
}